// Round 24
// baseline (65.266 us; speedup 1.0000x reference)
//
#include <hip/hip_runtime.h>
#include <hip/hip_bf16.h>

#define BB 2
#define TT 1024
#define DD 512
#define HH 8
#define FF 16
#define HDIM 64
#define BT (BB*TT)   // 2048

typedef short bf16x8 __attribute__((ext_vector_type(8)));
typedef float f32x4  __attribute__((ext_vector_type(4)));
#define MFMA_BF16 __builtin_amdgcn_mfma_f32_16x16x32_bf16

// float -> bf16 round-to-nearest-even (scalar)
__device__ __forceinline__ ushort f2b(float f) {
    uint u = __float_as_uint(f);
    uint r = (u + 0x7fffu + ((u >> 16) & 1u)) >> 16;
    return (ushort)r;
}

// pack two floats -> one dword of 2 bf16
__device__ __forceinline__ uint pkbf2(float a, float b) {
    __hip_bfloat162 h = __float22bfloat162_rn(make_float2(a, b));
    union { __hip_bfloat162 h2; uint u; } c; c.h2 = h;
    return c.u;
}

__device__ __forceinline__ uint get_xcc() {
    uint x;
    asm volatile("s_getreg_b32 %0, hwreg(HW_REG_XCC_ID)" : "=s"(x));
    return x & 7u;
}

// ---------------------------------------------------------------------------
// Kernel 1: FUSED cast + QKV projection (round-23 body, unchanged).
// ---------------------------------------------------------------------------
__global__ __launch_bounds__(512) void qkv_f32(
    const float* __restrict__ X,  const float* __restrict__ Wq,
    const float* __restrict__ Wk, const float* __restrict__ Wv,
    const float* __restrict__ Wo,
    ushort* __restrict__ Qb, ushort* __restrict__ Kb,
    ushort* __restrict__ Vtg, ushort* __restrict__ Wob)
{
    if (blockIdx.y == 6) {   // Wo cast tail: 16 blocks x 512 thr x 8 float4
        const int idx = blockIdx.x * 512 + threadIdx.x;   // 0..8191
        #pragma unroll
        for (int j = 0; j < 8; ++j) {
            const int u = j * 8192 + idx;                 // 0..65535 float4s
            float4 v = *(const float4*)(Wo + (size_t)u * 4);
            ushort4 o = { f2b(v.x), f2b(v.y), f2b(v.z), f2b(v.w) };
            *(ushort4*)(Wob + (size_t)u * 4) = o;
        }
        return;
    }

    __shared__ short LA[128][136];   // 34.8KB, +8 pad
    __shared__ short LB[128][136];   // 34.8KB

    const int m0 = blockIdx.x * 128;
    const int by = blockIdx.y;
    const int tid = threadIdx.x, w = tid >> 6, l = tid & 63;
    const int mw = w & 3, nw = w >> 2;      // 4 m-waves x 2 n-waves
    const int lr = l & 15, g = l >> 4;

    const float* Wsrc = (by == 0) ? Wq
                      : (by == 1) ? Wk
                      : (Wv + (size_t)(by - 2) * 128 * 512);

    f32x4 acc[2][4] = {};

    for (int kc = 0; kc < 4; ++kc) {
        __syncthreads();   // previous chunk's fragment reads done
        #pragma unroll
        for (int i = 0; i < 8; ++i) {
            const int f = i * 512 + tid;          // float4 idx 0..4095
            const int row = f >> 5, c4 = f & 31;  // 32 float4 per row
            float4 va = *(const float4*)(X + (size_t)(m0 + row) * 512 + kc*128 + c4*4);
            uint2 pa = { pkbf2(va.x, va.y), pkbf2(va.z, va.w) };
            *(uint2*)&LA[row][c4*4] = pa;
            float4 vb = *(const float4*)(Wsrc + (size_t)row * 512 + kc*128 + c4*4);
            uint2 pb = { pkbf2(vb.x, vb.y), pkbf2(vb.z, vb.w) };
            *(uint2*)&LB[row][c4*4] = pb;
        }
        __syncthreads();

        #pragma unroll
        for (int ks = 0; ks < 4; ++ks) {
            bf16x8 a0 = *(const bf16x8*)&LA[mw*32      + lr][ks*32 + g*8];
            bf16x8 a1 = *(const bf16x8*)&LA[mw*32 + 16 + lr][ks*32 + g*8];
            bf16x8 b0 = *(const bf16x8*)&LB[nw*64      + lr][ks*32 + g*8];
            bf16x8 b1 = *(const bf16x8*)&LB[nw*64 + 16 + lr][ks*32 + g*8];
            bf16x8 b2 = *(const bf16x8*)&LB[nw*64 + 32 + lr][ks*32 + g*8];
            bf16x8 b3 = *(const bf16x8*)&LB[nw*64 + 48 + lr][ks*32 + g*8];
            acc[0][0] = MFMA_BF16(a0, b0, acc[0][0], 0, 0, 0);
            acc[0][1] = MFMA_BF16(a0, b1, acc[0][1], 0, 0, 0);
            acc[0][2] = MFMA_BF16(a0, b2, acc[0][2], 0, 0, 0);
            acc[0][3] = MFMA_BF16(a0, b3, acc[0][3], 0, 0, 0);
            acc[1][0] = MFMA_BF16(a1, b0, acc[1][0], 0, 0, 0);
            acc[1][1] = MFMA_BF16(a1, b1, acc[1][1], 0, 0, 0);
            acc[1][2] = MFMA_BF16(a1, b2, acc[1][2], 0, 0, 0);
            acc[1][3] = MFMA_BF16(a1, b3, acc[1][3], 0, 0, 0);
        }
    }

    if (by < 2) {
        ushort* Dst = (by == 0) ? Qb : Kb;
        const float scale = (by == 0) ? 1.0f : 0.25f;   // K pre-scaled 1/4
        #pragma unroll
        for (int mb = 0; mb < 2; ++mb)
            #pragma unroll
            for (int nb = 0; nb < 4; ++nb) {
                const int n = nw*64 + nb*16 + lr;
                const int h = n >> 4, fc = n & 15;
                #pragma unroll
                for (int r = 0; r < 4; ++r) {
                    const int tok = m0 + mw*32 + mb*16 + g*4 + r;
                    const int b = tok >> 10, tt = tok & 1023;
                    Dst[((size_t)(b*HH + h)*TT + tt)*FF + fc] =
                        f2b(acc[mb][nb][r] * scale);
                }
            }
    } else {
        #pragma unroll
        for (int mb = 0; mb < 2; ++mb)
            #pragma unroll
            for (int nb = 0; nb < 4; ++nb) {
                const int n = (by - 2)*128 + nw*64 + nb*16 + lr;
                const int h = n >> 6, v = n & 63;
                const int tok0 = m0 + mw*32 + mb*16 + g*4;
                const int b = tok0 >> 10, tt0 = tok0 & 1023;
                uint2 pk = { pkbf2(acc[mb][nb][0], acc[mb][nb][1]),
                             pkbf2(acc[mb][nb][2], acc[mb][nb][3]) };
                *(uint2*)&Vtg[((size_t)(b*HH + h)*64 + v)*TT + tt0] = pk;
            }
    }
}

// ---------------------------------------------------------------------------
// Kernel 2: FUSED attention + output projection, one in-kernel grid barrier.
// Grid 512 x 512 thr; LDS 70.7KB -> exactly 2 blocks/CU -> all 512 blocks
// co-resident by construction (barrier precondition).
// Phase A: attention (round-21/23 body, unchanged).
// Barrier: round-19/20-proven hierarchical protocol, target 512: distributed
//   per-XCD arrive counters; per-XCD CAS winner polls sum>=512, reads NX
//   (census), __threadfence (8 parallel wbl2+inv publishes/invalidates Yb
//   across XCD L2s), incs F, polls F>=NX, sets R[x]; others poll R[own-XCD].
// Phase B: out projection, 512 blocks of 32x64 tiles (round-10/11-proven
//   body: 8 waves = 2n x 4k, K=128/wave, LDS combine of 4 K-partials).
// ---------------------------------------------------------------------------
__global__ __launch_bounds__(512) void attn_out(
    const ushort* __restrict__ Qb, const ushort* __restrict__ Kb,
    const ushort* __restrict__ Vtg, const ushort* __restrict__ Wob,
    ushort* __restrict__ Yb, float* __restrict__ Out,
    unsigned long long* __restrict__ Bar)
{
    __shared__ float smem[8*32*68 + 8*32];           // 70656 B, aliased
    short (*Pl)[32][72] = (short(*)[32][72])smem;    // attn: [wave][q32][k64+8]
    float* scf = smem;                               // attn epi: [8][32][68]
    float* scd = smem + 8*32*68;                     // attn epi: [8][32]

    unsigned long long* B = Bar;
    uint* S = (uint*)(Bar + 144);

    const int bid = blockIdx.x;
    const int tid = threadIdx.x, w = tid >> 6, l = tid & 63;
    const int lr = l & 15, g = l >> 4;
    const uint xcd = get_xcc();

    // census: NX (#populated XCDs) final before any winner reads it
    if (tid == 0) {
        if (atomicCAS(&S[xcd], 0u, 1u) == 0u) {
            unsigned long long r = atomicAdd(&B[4], 1ull);
            asm volatile("" :: "v"((uint)r));
        }
    }

    // ---------------- phase A: attention ----------------
    {
        const int qt = 31 - (bid >> 4);       // heavy q-tiles first (LPT)
        const int bh = bid & 15;
        const int b = bh >> 3, h = bh & 7;
        const int qend = qt*32 + 32;
        const int nkc = (qt + 2) >> 1;        // ceil(qend/64)
        const bf16x8 zf = {0,0,0,0,0,0,0,0};
        const bf16x8 ones = {16256,16256,16256,16256,16256,16256,16256,16256};

        bf16x8 qf[2];
        #pragma unroll
        for (int nb = 0; nb < 2; ++nb)
            qf[nb] = (l < 32)
                ? *(const bf16x8*)(Qb + ((size_t)bh*TT + qt*32 + nb*16 + lr)*FF + g*8)
                : zf;

        f32x4 o[4][2] = {};
        f32x4 dacc[2] = {};

        for (int kc = w; kc < nkc; kc += 8) {
            const bool diagc = (kc == nkc - 1);
            const int act = qend - kc*64;
            const int nmb = diagc ? (act >> 4) : 4;   // 2 or 4 (even)
            const int kb_max = nmb >> 1;

            for (int mb = 0; mb < nmb; ++mb) {
                bf16x8 kf = (l < 32)
                    ? *(const bf16x8*)(Kb + ((size_t)bh*TT + kc*64 + mb*16 + lr)*FF + g*8)
                    : zf;
                #pragma unroll
                for (int nb = 0; nb < 2; ++nb) {
                    f32x4 z4 = {};
                    f32x4 s = MFMA_BF16(kf, qf[nb], z4, 0, 0, 0);  // pre-scaled
                    float pv[4];
                    if (diagc) {
                        const int qg = qt*32 + nb*16 + lr;
                        const int kg0 = kc*64 + mb*16 + g*4;
                        #pragma unroll
                        for (int r = 0; r < 4; ++r) {
                            float pp = fmaf(s[r], fmaf(s[r], 0.5f, 1.0f), 1.0f);
                            pv[r] = (kg0 + r > qg) ? 0.f : pp;
                        }
                    } else {
                        #pragma unroll
                        for (int r = 0; r < 4; ++r)
                            pv[r] = fmaf(s[r], fmaf(s[r], 0.5f, 1.0f), 1.0f);
                    }
                    uint2 pk = { pkbf2(pv[0], pv[1]), pkbf2(pv[2], pv[3]) };
                    *(uint2*)&Pl[w][nb*16 + lr][mb*16 + g*4] = pk;
                }
            }

            for (int kb = 0; kb < kb_max; ++kb) {
                #pragma unroll
                for (int mv = 0; mv < 4; ++mv) {
                    bf16x8 vf = *(const bf16x8*)(Vtg +
                        ((size_t)bh*64 + mv*16 + lr)*TT + kc*64 + kb*32 + g*8);
                    #pragma unroll
                    for (int nb = 0; nb < 2; ++nb) {
                        bf16x8 pf = *(const bf16x8*)&Pl[w][nb*16 + lr][kb*32 + g*8];
                        o[mv][nb] = MFMA_BF16(vf, pf, o[mv][nb], 0, 0, 0);
                    }
                }
                #pragma unroll
                for (int nb = 0; nb < 2; ++nb) {
                    bf16x8 pf = *(const bf16x8*)&Pl[w][nb*16 + lr][kb*32 + g*8];
                    dacc[nb] = MFMA_BF16(ones, pf, dacc[nb], 0, 0, 0);
                }
            }
        }

        __syncthreads();   // all waves done with Pl (scratch overlays it)

        #pragma unroll
        for (int mv = 0; mv < 4; ++mv)
            #pragma unroll
            for (int nb = 0; nb < 2; ++nb)
                *(f32x4*)&scf[(size_t)(w*32 + nb*16 + lr)*68 + mv*16 + g*4] = o[mv][nb];
        if (g == 0) {
            scd[w*32 + lr]      = dacc[0][0];
            scd[w*32 + 16 + lr] = dacc[1][0];
        }

        __syncthreads();

        {
            const int q  = tid >> 4;           // 0..31
            const int v0 = (tid & 15) * 4;     // 0..60
            float dtot = 0.f;
            #pragma unroll
            for (int ww = 0; ww < 8; ++ww) dtot += scd[ww*32 + q];
            const float inv = 1.0f / (dtot + 1e-12f);
            float o0 = 0.f, o1 = 0.f, o2 = 0.f, o3 = 0.f;
            #pragma unroll
            for (int ww = 0; ww < 8; ++ww) {
                const float* p = &scf[(size_t)(ww*32 + q)*68 + v0];
                o0 += p[0]; o1 += p[1]; o2 += p[2]; o3 += p[3];
            }
            uint2 pk = { pkbf2(o0*inv, o1*inv), pkbf2(o2*inv, o3*inv) };
            *(uint2*)(Yb + ((size_t)(b*TT + qt*32 + q))*DD + h*HDIM + v0) = pk;
        }
    }

    // ---------------- grid barrier (target 512 blocks) ----------------
    __syncthreads();                    // Yb stores drained to local L2
    if (tid == 0) {
        atomicAdd(&B[80 + (size_t)xcd * 8], 1ull);   // distributed arrive
        if (atomicCAS(&S[8 + xcd], 0u, 1u) == 0u) {
            for (;;) {
                unsigned long long ssum = 0;
                #pragma unroll
                for (int x = 0; x < 8; ++x)
                    ssum += __hip_atomic_load(&B[80 + (size_t)x * 8],
                                              __ATOMIC_RELAXED,
                                              __HIP_MEMORY_SCOPE_SYSTEM);
                if (ssum >= 512ull) break;
                __builtin_amdgcn_s_sleep(2);
            }
            const unsigned long long NX =
                __hip_atomic_load(&B[4], __ATOMIC_RELAXED,
                                  __HIP_MEMORY_SCOPE_SYSTEM);
            __threadfence();            // one wbl2+inv per XCD, in parallel
            atomicAdd(&B[1], 1ull);
            while (__hip_atomic_load(&B[1], __ATOMIC_RELAXED,
                                     __HIP_MEMORY_SCOPE_SYSTEM) < NX)
                __builtin_amdgcn_s_sleep(2);
            __hip_atomic_store(&B[8 + (size_t)xcd * 8], 1ull,
                               __ATOMIC_RELAXED, __HIP_MEMORY_SCOPE_SYSTEM);
        }
        while (__hip_atomic_load(&B[8 + (size_t)xcd * 8], __ATOMIC_RELAXED,
                                 __HIP_MEMORY_SCOPE_SYSTEM) < 1ull)
            __builtin_amdgcn_s_sleep(2);
    }
    __syncthreads();

    // ---------------- phase B: output projection (32x64 tiles) ----------------
    {
        float (*sc)[32][66] = (float(*)[32][66])smem;    // [4][32][66] 33.8KB
        const int m0 = (bid >> 3) * 32, n0 = (bid & 7) * 64;
        const int nw = w & 1, kw = w >> 1;               // 2n x 4k waves

        f32x4 acc[2][2] = {};
        const ushort* Ar = Yb  + (size_t)(m0 + lr) * 512 + kw*128 + g*8;
        const ushort* Br = Wob + (size_t)(n0 + nw*32 + lr) * 512 + kw*128 + g*8;

        #pragma unroll
        for (int ks = 0; ks < 4; ++ks) {
            bf16x8 a0 = *(const bf16x8*)(Ar + ks*32);
            bf16x8 a1 = *(const bf16x8*)(Ar + (size_t)16*512 + ks*32);
            bf16x8 b0 = *(const bf16x8*)(Br + ks*32);
            bf16x8 b1 = *(const bf16x8*)(Br + (size_t)16*512 + ks*32);
            acc[0][0] = MFMA_BF16(a0, b0, acc[0][0], 0, 0, 0);
            acc[0][1] = MFMA_BF16(a0, b1, acc[0][1], 0, 0, 0);
            acc[1][0] = MFMA_BF16(a1, b0, acc[1][0], 0, 0, 0);
            acc[1][1] = MFMA_BF16(a1, b1, acc[1][1], 0, 0, 0);
        }

        #pragma unroll
        for (int mb = 0; mb < 2; ++mb)
            #pragma unroll
            for (int nb = 0; nb < 2; ++nb)
                #pragma unroll
                for (int r = 0; r < 4; ++r)
                    sc[kw][mb*16 + g*4 + r][nw*32 + nb*16 + lr] = acc[mb][nb][r];
        __syncthreads();

        const int row = tid >> 4, c0 = (tid & 15) * 4;
        float4 v;
        v.x = sc[0][row][c0+0] + sc[1][row][c0+0] + sc[2][row][c0+0] + sc[3][row][c0+0];
        v.y = sc[0][row][c0+1] + sc[1][row][c0+1] + sc[2][row][c0+1] + sc[3][row][c0+1];
        v.z = sc[0][row][c0+2] + sc[1][row][c0+2] + sc[2][row][c0+2] + sc[3][row][c0+2];
        v.w = sc[0][row][c0+3] + sc[1][row][c0+3] + sc[2][row][c0+3] + sc[3][row][c0+3];
        *(float4*)(Out + (size_t)(m0 + row)*512 + n0 + c0) = v;
    }
}

// ---------------------------------------------------------------------------
extern "C" void kernel_launch(void* const* d_in, const int* in_sizes, int n_in,
                              void* d_out, int out_size, void* d_ws, size_t ws_size,
                              hipStream_t stream) {
    const float* X  = (const float*)d_in[0];   // (2,1024,512)
    const float* Wq = (const float*)d_in[1];   // (128,512)
    const float* Wk = (const float*)d_in[2];   // (128,512)
    const float* Wv = (const float*)d_in[3];   // (512,512)
    const float* Wo = (const float*)d_in[4];   // (512,512)
    float* out = (float*)d_out;                // (2,1024,512)

    ushort* ws = (ushort*)d_ws;
    ushort* Wob = ws;                    // 512*512    = 262144
    ushort* Qb  = Wob + 262144;          // 16*1024*16 = 262144
    ushort* Kb  = Qb  + 262144;          // 262144
    ushort* Vtg = Kb  + 262144;          // 16*64*1024 = 1048576
    ushort* Yb  = Vtg + 1048576;         // 2048*512   = 1048576
    unsigned long long* Bar = (unsigned long long*)(ws + 2883584); // 8-aligned
    // B[0..143] u64 (F @1, NX @4, R[x] @8+8x, Ax[x] @80+8x) | S[0..31] u32

    // zero barrier state every call (graph-capture-legal, replay-safe)
    hipMemsetAsync((void*)Bar, 0, 1280, stream);

    dim3 g1(16, 7);           // 16x6 fused cast+QKV tiles + 16x1 Wo-cast
    qkv_f32<<<g1, 512, 0, stream>>>(X, Wq, Wk, Wv, Wo, Qb, Kb, Vtg, Wob);

    attn_out<<<512, 512, 0, stream>>>(Qb, Kb, Vtg, Wob, Yb, out, Bar);
}

// Round 25
// 43.027 us; speedup vs baseline: 1.5169x; 1.5169x over previous
//
#include <hip/hip_runtime.h>
#include <hip/hip_bf16.h>

#define BB 2
#define TT 1024
#define DD 512
#define HH 8
#define FF 16
#define HDIM 64
#define BT (BB*TT)   // 2048

typedef short bf16x8 __attribute__((ext_vector_type(8)));
typedef float f32x4  __attribute__((ext_vector_type(4)));
#define MFMA_BF16 __builtin_amdgcn_mfma_f32_16x16x32_bf16

// float -> bf16 round-to-nearest-even (scalar)
__device__ __forceinline__ ushort f2b(float f) {
    uint u = __float_as_uint(f);
    uint r = (u + 0x7fffu + ((u >> 16) & 1u)) >> 16;
    return (ushort)r;
}

// pack two floats -> one dword of 2 bf16
__device__ __forceinline__ uint pkbf2(float a, float b) {
    __hip_bfloat162 h = __float22bfloat162_rn(make_float2(a, b));
    union { __hip_bfloat162 h2; uint u; } c; c.h2 = h;
    return c.u;
}

// ---------------------------------------------------------------------------
// Kernel 1: FUSED cast + QKV projection (kills the cast dispatch).
// Grid (16, 7): by 0..5 = 128x128 GEMM tiles (by0=Q, by1=K, by2-5=V);
// by==6 = Wo->bf16 cast tail (16 blocks).
// Per block: K processed in 4 chunks of 128; each chunk's X/W f32 panels are
// loaded ONCE (coalesced float4), converted to bf16 into LDS, and MFMA
// fragments read from LDS. 8 waves = 4m x 2n, wave tile 32x64, acc[2][4].
// Epilogue routes Q,K (K pre-scaled 1/4) -> (bh,t,16); V -> Vt[bh][64][1024].
// ---------------------------------------------------------------------------
__global__ __launch_bounds__(512) void qkv_f32(
    const float* __restrict__ X,  const float* __restrict__ Wq,
    const float* __restrict__ Wk, const float* __restrict__ Wv,
    const float* __restrict__ Wo,
    ushort* __restrict__ Qb, ushort* __restrict__ Kb,
    ushort* __restrict__ Vtg, ushort* __restrict__ Wob)
{
    if (blockIdx.y == 6) {   // Wo cast tail: 16 blocks x 512 thr x 8 float4
        const int idx = blockIdx.x * 512 + threadIdx.x;   // 0..8191
        #pragma unroll
        for (int j = 0; j < 8; ++j) {
            const int u = j * 8192 + idx;                 // 0..65535 float4s
            float4 v = *(const float4*)(Wo + (size_t)u * 4);
            ushort4 o = { f2b(v.x), f2b(v.y), f2b(v.z), f2b(v.w) };
            *(ushort4*)(Wob + (size_t)u * 4) = o;
        }
        return;
    }

    __shared__ short LA[128][136];   // 34.8KB, +8 pad
    __shared__ short LB[128][136];   // 34.8KB

    const int m0 = blockIdx.x * 128;
    const int by = blockIdx.y;
    const int tid = threadIdx.x, w = tid >> 6, l = tid & 63;
    const int mw = w & 3, nw = w >> 2;      // 4 m-waves x 2 n-waves
    const int lr = l & 15, g = l >> 4;

    const float* Wsrc = (by == 0) ? Wq
                      : (by == 1) ? Wk
                      : (Wv + (size_t)(by - 2) * 128 * 512);

    f32x4 acc[2][4] = {};

    for (int kc = 0; kc < 4; ++kc) {
        __syncthreads();   // previous chunk's fragment reads done
        // stage 128x128 f32 chunks of X and Wsrc -> bf16 LDS (coalesced)
        #pragma unroll
        for (int i = 0; i < 8; ++i) {
            const int f = i * 512 + tid;          // float4 idx 0..4095
            const int row = f >> 5, c4 = f & 31;  // 32 float4 per row
            float4 va = *(const float4*)(X + (size_t)(m0 + row) * 512 + kc*128 + c4*4);
            uint2 pa = { pkbf2(va.x, va.y), pkbf2(va.z, va.w) };
            *(uint2*)&LA[row][c4*4] = pa;
            float4 vb = *(const float4*)(Wsrc + (size_t)row * 512 + kc*128 + c4*4);
            uint2 pb = { pkbf2(vb.x, vb.y), pkbf2(vb.z, vb.w) };
            *(uint2*)&LB[row][c4*4] = pb;
        }
        __syncthreads();

        #pragma unroll
        for (int ks = 0; ks < 4; ++ks) {
            bf16x8 a0 = *(const bf16x8*)&LA[mw*32      + lr][ks*32 + g*8];
            bf16x8 a1 = *(const bf16x8*)&LA[mw*32 + 16 + lr][ks*32 + g*8];
            bf16x8 b0 = *(const bf16x8*)&LB[nw*64      + lr][ks*32 + g*8];
            bf16x8 b1 = *(const bf16x8*)&LB[nw*64 + 16 + lr][ks*32 + g*8];
            bf16x8 b2 = *(const bf16x8*)&LB[nw*64 + 32 + lr][ks*32 + g*8];
            bf16x8 b3 = *(const bf16x8*)&LB[nw*64 + 48 + lr][ks*32 + g*8];
            acc[0][0] = MFMA_BF16(a0, b0, acc[0][0], 0, 0, 0);
            acc[0][1] = MFMA_BF16(a0, b1, acc[0][1], 0, 0, 0);
            acc[0][2] = MFMA_BF16(a0, b2, acc[0][2], 0, 0, 0);
            acc[0][3] = MFMA_BF16(a0, b3, acc[0][3], 0, 0, 0);
            acc[1][0] = MFMA_BF16(a1, b0, acc[1][0], 0, 0, 0);
            acc[1][1] = MFMA_BF16(a1, b1, acc[1][1], 0, 0, 0);
            acc[1][2] = MFMA_BF16(a1, b2, acc[1][2], 0, 0, 0);
            acc[1][3] = MFMA_BF16(a1, b3, acc[1][3], 0, 0, 0);
        }
    }

    if (by < 2) {
        // Q (by==0) or K (by==1): features 0..127 -> h = n>>4, f = n&15
        ushort* Dst = (by == 0) ? Qb : Kb;
        const float scale = (by == 0) ? 1.0f : 0.25f;   // K pre-scaled 1/4
        #pragma unroll
        for (int mb = 0; mb < 2; ++mb)
            #pragma unroll
            for (int nb = 0; nb < 4; ++nb) {
                const int n = nw*64 + nb*16 + lr;
                const int h = n >> 4, fc = n & 15;
                #pragma unroll
                for (int r = 0; r < 4; ++r) {
                    const int tok = m0 + mw*32 + mb*16 + g*4 + r;
                    const int b = tok >> 10, tt = tok & 1023;
                    Dst[((size_t)(b*HH + h)*TT + tt)*FF + fc] =
                        f2b(acc[mb][nb][r] * scale);
                }
            }
    } else {
        // V: features (by-2)*128 + .. in 0..511 -> h = n>>6, v = n&63
        #pragma unroll
        for (int mb = 0; mb < 2; ++mb)
            #pragma unroll
            for (int nb = 0; nb < 4; ++nb) {
                const int n = (by - 2)*128 + nw*64 + nb*16 + lr;
                const int h = n >> 6, v = n & 63;
                const int tok0 = m0 + mw*32 + mb*16 + g*4;
                const int b = tok0 >> 10, tt0 = tok0 & 1023;
                uint2 pk = { pkbf2(acc[mb][nb][0], acc[mb][nb][1]),
                             pkbf2(acc[mb][nb][2], acc[mb][nb][3]) };
                *(uint2*)&Vtg[((size_t)(b*HH + h)*64 + v)*TT + tt0] = pk;
            }
    }
}

// ---------------------------------------------------------------------------
// Kernel 2: causal Taylor attention, bf16 MFMA, 8-wave split-K:
// 32 q-rows/block, 512 blocks (LPT), VALU diet + den-MFMA.
// phi(q).phi(k) = 1 + s + s^2/2, s = q.k_scaled (K pre-scaled 1/4).
// ---------------------------------------------------------------------------
__global__ __launch_bounds__(512) void attn_mfma(
    const ushort* __restrict__ Qb, const ushort* __restrict__ Kb,
    const ushort* __restrict__ Vtg, ushort* __restrict__ Yb)
{
    __shared__ float smem[8*32*68 + 8*32];           // 70656 B
    short (*Pl)[32][72] = (short(*)[32][72])smem;    // [wave][q32][k64+8]
    float* scf = smem;                               // epi: [8][32][68]
    float* scd = smem + 8*32*68;                     // epi: [8][32]

    const int bid = blockIdx.x;
    const int qt = 31 - (bid >> 4);       // heavy q-tiles dispatch first (LPT)
    const int bh = bid & 15;
    const int b = bh >> 3, h = bh & 7;
    const int tid = threadIdx.x, w = tid >> 6, l = tid & 63;
    const int lr = l & 15, g = l >> 4;
    const int qend = qt*32 + 32;
    const int nkc = (qt + 2) >> 1;        // ceil(qend/64)
    const bf16x8 zf = {0,0,0,0,0,0,0,0};
    const bf16x8 ones = {16256,16256,16256,16256,16256,16256,16256,16256}; // bf16 1.0

    bf16x8 qf[2];
    #pragma unroll
    for (int nb = 0; nb < 2; ++nb)
        qf[nb] = (l < 32)
            ? *(const bf16x8*)(Qb + ((size_t)bh*TT + qt*32 + nb*16 + lr)*FF + g*8)
            : zf;

    f32x4 o[4][2] = {};       // o[mv][nb]: O^T partial over this wave's kc set
    f32x4 dacc[2] = {};       // den[q=lr] per nb (replicated across regs)

    for (int kc = w; kc < nkc; kc += 8) {
        const bool diagc = (kc == nkc - 1);           // wave-uniform
        const int act = qend - kc*64;
        const int nmb = diagc ? (act >> 4) : 4;       // 2 or 4 (always even)
        const int kb_max = nmb >> 1;                  // 1 or 2

        for (int mb = 0; mb < nmb; ++mb) {
            bf16x8 kf = (l < 32)
                ? *(const bf16x8*)(Kb + ((size_t)bh*TT + kc*64 + mb*16 + lr)*FF + g*8)
                : zf;
            #pragma unroll
            for (int nb = 0; nb < 2; ++nb) {
                f32x4 z4 = {};
                f32x4 s = MFMA_BF16(kf, qf[nb], z4, 0, 0, 0);  // s pre-scaled
                float pv[4];
                if (diagc) {
                    const int qg = qt*32 + nb*16 + lr;
                    const int kg0 = kc*64 + mb*16 + g*4;
                    #pragma unroll
                    for (int r = 0; r < 4; ++r) {
                        float pp = fmaf(s[r], fmaf(s[r], 0.5f, 1.0f), 1.0f);
                        pv[r] = (kg0 + r > qg) ? 0.f : pp;
                    }
                } else {
                    #pragma unroll
                    for (int r = 0; r < 4; ++r)
                        pv[r] = fmaf(s[r], fmaf(s[r], 0.5f, 1.0f), 1.0f);
                }
                uint2 pk = { pkbf2(pv[0], pv[1]), pkbf2(pv[2], pv[3]) };
                *(uint2*)&Pl[w][nb*16 + lr][mb*16 + g*4] = pk;
            }
        }

        for (int kb = 0; kb < kb_max; ++kb) {
            #pragma unroll
            for (int mv = 0; mv < 4; ++mv) {
                bf16x8 vf = *(const bf16x8*)(Vtg +
                    ((size_t)bh*64 + mv*16 + lr)*TT + kc*64 + kb*32 + g*8);
                #pragma unroll
                for (int nb = 0; nb < 2; ++nb) {
                    bf16x8 pf = *(const bf16x8*)&Pl[w][nb*16 + lr][kb*32 + g*8];
                    o[mv][nb] = MFMA_BF16(vf, pf, o[mv][nb], 0, 0, 0);
                }
            }
            #pragma unroll
            for (int nb = 0; nb < 2; ++nb) {
                bf16x8 pf = *(const bf16x8*)&Pl[w][nb*16 + lr][kb*32 + g*8];
                dacc[nb] = MFMA_BF16(ones, pf, dacc[nb], 0, 0, 0);
            }
        }
    }

    __syncthreads();   // all waves done with Pl (scratch overlays it)

    #pragma unroll
    for (int mv = 0; mv < 4; ++mv)
        #pragma unroll
        for (int nb = 0; nb < 2; ++nb)
            *(f32x4*)&scf[(size_t)(w*32 + nb*16 + lr)*68 + mv*16 + g*4] = o[mv][nb];
    if (g == 0) {
        scd[w*32 + lr]      = dacc[0][0];
        scd[w*32 + 16 + lr] = dacc[1][0];
    }

    __syncthreads();

    {
        const int q  = tid >> 4;           // 0..31
        const int v0 = (tid & 15) * 4;     // 0..60
        float dtot = 0.f;
        #pragma unroll
        for (int ww = 0; ww < 8; ++ww) dtot += scd[ww*32 + q];
        const float inv = 1.0f / (dtot + 1e-12f);
        float o0 = 0.f, o1 = 0.f, o2 = 0.f, o3 = 0.f;
        #pragma unroll
        for (int ww = 0; ww < 8; ++ww) {
            const float* p = &scf[(size_t)(ww*32 + q)*68 + v0];
            o0 += p[0]; o1 += p[1]; o2 += p[2]; o3 += p[3];
        }
        uint2 pk = { pkbf2(o0*inv, o1*inv), pkbf2(o2*inv, o3*inv) };
        *(uint2*)(Yb + ((size_t)(b*TT + qt*32 + q))*DD + h*HDIM + v0) = pk;
    }
}

// ---------------------------------------------------------------------------
// Kernel 3: output projection, bf16 MFMA, K-split 8-wave.
// Out[2048 x 512] = Yb @ Wob^T (f32 out).
// ---------------------------------------------------------------------------
__global__ __launch_bounds__(512) void out_mfma(
    const ushort* __restrict__ Yb, const ushort* __restrict__ Wob,
    float* __restrict__ Out)
{
    __shared__ float sc[2][64][66];
    const int m0 = blockIdx.x * 64, n0 = blockIdx.y * 64;
    const int tid = threadIdx.x, w = tid >> 6, l = tid & 63;
    const int kw = w >> 2, mw = w & 1, nw = (w >> 1) & 1;
    const int lr = l & 15, g = l >> 4;

    f32x4 acc[2][2] = {};
    const ushort* Ar = Yb  + (size_t)(m0 + mw*32 + lr) * 512 + kw*256 + g*8;
    const ushort* Br = Wob + (size_t)(n0 + nw*32 + lr) * 512 + kw*256 + g*8;

    bf16x8 a0c = *(const bf16x8*)(Ar);
    bf16x8 a1c = *(const bf16x8*)(Ar + (size_t)16*512);
    bf16x8 b0c = *(const bf16x8*)(Br);
    bf16x8 b1c = *(const bf16x8*)(Br + (size_t)16*512);
    #pragma unroll
    for (int ks = 0; ks < 8; ++ks) {
        bf16x8 a0n = a0c, a1n = a1c, b0n = b0c, b1n = b1c;
        if (ks < 7) {
            a0n = *(const bf16x8*)(Ar + (ks+1)*32);
            a1n = *(const bf16x8*)(Ar + (size_t)16*512 + (ks+1)*32);
            b0n = *(const bf16x8*)(Br + (ks+1)*32);
            b1n = *(const bf16x8*)(Br + (size_t)16*512 + (ks+1)*32);
        }
        acc[0][0] = MFMA_BF16(a0c, b0c, acc[0][0], 0, 0, 0);
        acc[0][1] = MFMA_BF16(a0c, b1c, acc[0][1], 0, 0, 0);
        acc[1][0] = MFMA_BF16(a1c, b0c, acc[1][0], 0, 0, 0);
        acc[1][1] = MFMA_BF16(a1c, b1c, acc[1][1], 0, 0, 0);
        a0c = a0n; a1c = a1n; b0c = b0n; b1c = b1n;
    }

    #pragma unroll
    for (int mb = 0; mb < 2; ++mb)
        #pragma unroll
        for (int nb = 0; nb < 2; ++nb)
            #pragma unroll
            for (int r = 0; r < 4; ++r)
                sc[kw][mw*32 + mb*16 + g*4 + r][nw*32 + nb*16 + lr] = acc[mb][nb][r];
    __syncthreads();

    const int vl = tid & 63, rg = tid >> 6;
    #pragma unroll
    for (int j = 0; j < 8; ++j) {
        const float v = sc[0][rg*8 + j][vl] + sc[1][rg*8 + j][vl];
        Out[(size_t)(m0 + rg*8 + j)*512 + n0 + vl] = v;
    }
}

// ---------------------------------------------------------------------------
extern "C" void kernel_launch(void* const* d_in, const int* in_sizes, int n_in,
                              void* d_out, int out_size, void* d_ws, size_t ws_size,
                              hipStream_t stream) {
    const float* X  = (const float*)d_in[0];   // (2,1024,512)
    const float* Wq = (const float*)d_in[1];   // (128,512)
    const float* Wk = (const float*)d_in[2];   // (128,512)
    const float* Wv = (const float*)d_in[3];   // (512,512)
    const float* Wo = (const float*)d_in[4];   // (512,512)
    float* out = (float*)d_out;                // (2,1024,512)

    ushort* ws = (ushort*)d_ws;
    ushort* Wob = ws;                    // 512*512    = 262144
    ushort* Qb  = Wob + 262144;          // 16*1024*16 = 262144
    ushort* Kb  = Qb  + 262144;          // 262144
    ushort* Vtg = Kb  + 262144;          // 16*64*1024 = 1048576
    ushort* Yb  = Vtg + 1048576;         // 2048*512   = 1048576
    // total 2,883,584 ushorts = 5.8 MB

    dim3 g1(16, 7);           // 16x6 fused cast+QKV tiles + 16x1 Wo-cast
    qkv_f32<<<g1, 512, 0, stream>>>(X, Wq, Wk, Wv, Wo, Qb, Kb, Vtg, Wob);

    attn_mfma<<<512, 512, 0, stream>>>(Qb, Kb, Vtg, Yb);

    dim3 g3(BT/64, DD/64);    // 32 x 8 = 256 blocks, 512 thr
    out_mfma<<<g3, 512, 0, stream>>>(Yb, Wob, out);
}